// Round 1
// baseline (319.384 us; speedup 1.0000x reference)
//
#include <hip/hip_runtime.h>

#define EMB 10
#define STATE 20
#define HIDDEN 40
#define NPROJ 2490

__device__ __forceinline__ float dot10(const float* __restrict__ t, const float wv[EMB]) {
    float2 t0 = *(const float2*)(t + 0);
    float2 t1 = *(const float2*)(t + 2);
    float2 t2 = *(const float2*)(t + 4);
    float2 t3 = *(const float2*)(t + 6);
    float2 t4 = *(const float2*)(t + 8);
    // two independent FMA chains for ILP
    float a = fmaf(wv[1], t0.y, wv[0] * t0.x);
    a = fmaf(wv[2], t1.x, a);
    a = fmaf(wv[3], t1.y, a);
    a = fmaf(wv[4], t2.x, a);
    float c = fmaf(wv[6], t3.x, wv[5] * t2.y);
    c = fmaf(wv[7], t3.y, c);
    c = fmaf(wv[8], t4.x, c);
    c = fmaf(wv[9], t4.y, c);
    return a + c;
}

__global__ __launch_bounds__(256, 4) void actor_kernel(
    const int* __restrict__ wid, const int* __restrict__ pid,
    const float* __restrict__ wemb, const float* __restrict__ pemb,
    const float* __restrict__ W1, const float* __restrict__ b1,
    const float* __restrict__ W2, const float* __restrict__ b2,
    int* __restrict__ out)
{
    const int lane = threadIdx.x & 63;
    const int wave = threadIdx.x >> 6;
    const int b = blockIdx.x * 64 + lane;

    // ---- gather x = [worker_emb[wid[b]], project_emb[pid[b]]] ----
    const int wi = wid[b];
    const int pi = pid[b];
    const float* __restrict__ wr = wemb + wi * EMB;
    const float* __restrict__ pr = pemb + pi * EMB;
    float x[STATE];
    #pragma unroll
    for (int k = 0; k < EMB / 2; ++k) {
        float2 v = *(const float2*)(wr + 2 * k);
        x[2 * k] = v.x; x[2 * k + 1] = v.y;
    }
    #pragma unroll
    for (int k = 0; k < EMB / 2; ++k) {
        float2 v = *(const float2*)(pr + 2 * k);
        x[EMB + 2 * k] = v.x; x[EMB + 2 * k + 1] = v.y;
    }

    // ---- layer 1: h = relu(W1 @ x + b1)  (W1 reads are wave-uniform -> cached) ----
    float h[HIDDEN];
    #pragma unroll 4
    for (int j = 0; j < HIDDEN; ++j) {
        float s = b1[j];
        #pragma unroll
        for (int k = 0; k < STATE; ++k) s = fmaf(W1[j * STATE + k], x[k], s);
        h[j] = fmaxf(s, 0.0f);
    }

    // ---- layer 2: wv = W2 @ h + b2 ----
    float wv[EMB];
    #pragma unroll
    for (int d = 0; d < EMB; ++d) {
        float s = b2[d];
        #pragma unroll
        for (int j = 0; j < HIDDEN; ++j) s = fmaf(W2[d * HIDDEN + j], h[j], s);
        wv[d] = s;
    }

    // ---- scan table rows 1..NPROJ-1, chunked across the block's 4 waves ----
    const int rows = NPROJ - 1;            // 2489
    const int per  = (rows + 3) / 4;       // 623
    int r0 = 1 + wave * per;
    int r1 = r0 + per; if (r1 > NPROJ) r1 = NPROJ;

    float best = -3.4e38f;
    int   bidx = 1;
    int n = r0;
    for (; n + 4 <= r1; n += 4) {
        float s0 = dot10(pemb + (n + 0) * EMB, wv);
        float s1 = dot10(pemb + (n + 1) * EMB, wv);
        float s2 = dot10(pemb + (n + 2) * EMB, wv);
        float s3 = dot10(pemb + (n + 3) * EMB, wv);
        if (s0 > best) { best = s0; bidx = n + 0; }
        if (s1 > best) { best = s1; bidx = n + 1; }
        if (s2 > best) { best = s2; bidx = n + 2; }
        if (s3 > best) { best = s3; bidx = n + 3; }
    }
    for (; n < r1; ++n) {
        float s = dot10(pemb + n * EMB, wv);
        if (s > best) { best = s; bidx = n; }
    }

    // ---- combine the 4 wave-chunks (ordered -> first-max tie-break preserved) ----
    __shared__ float sb[4][64];
    __shared__ int   si[4][64];
    sb[wave][lane] = best;
    si[wave][lane] = bidx;
    __syncthreads();
    if (wave == 0) {
        float bb = sb[0][lane];
        int   bi = si[0][lane];
        #pragma unroll
        for (int k = 1; k < 4; ++k) {
            float v  = sb[k][lane];
            int   vi = si[k][lane];
            if (v > bb) { bb = v; bi = vi; }
        }
        out[b] = bi;   // table row index == argmax + 1 already
    }
}

extern "C" void kernel_launch(void* const* d_in, const int* in_sizes, int n_in,
                              void* d_out, int out_size, void* d_ws, size_t ws_size,
                              hipStream_t stream) {
    const int*   wid  = (const int*)  d_in[0];
    const int*   pid  = (const int*)  d_in[1];
    const float* wemb = (const float*)d_in[2];
    const float* pemb = (const float*)d_in[3];
    const float* W1   = (const float*)d_in[4];
    const float* b1   = (const float*)d_in[5];
    const float* W2   = (const float*)d_in[6];
    const float* b2   = (const float*)d_in[7];
    int* out = (int*)d_out;

    const int B = in_sizes[0];             // 65536
    actor_kernel<<<B / 64, 256, 0, stream>>>(wid, pid, wemb, pemb, W1, b1, W2, b2, out);
}

// Round 2
// 165.099 us; speedup vs baseline: 1.9345x; 1.9345x over previous
//
#include <hip/hip_runtime.h>
#include <float.h>

using v2f = __attribute__((ext_vector_type(2))) float;
using v4f = __attribute__((ext_vector_type(4))) float;

#define EMB 10
#define STATE 20
#define HIDDEN 40
#define NPROJ 2490

#define ROWS_A 1246               // chunk A = table rows [0, 1246)
#define ROWS_B (NPROJ - ROWS_A)   // 1244 = rows [1246, 2490)
#define F4_A ((ROWS_A * 10) / 4)  // 3115 float4s (12460 floats, 16B-aligned base)
#define F4_B ((ROWS_B * 10) / 4)  // 3110 float4s (global byte base 49840 % 16 == 0)

// Scan LDS rows [lo, hi) (local indices, 10 floats @ stride 40B), row pairs read as
// 5x ds_read_b128 (uniform address -> broadcast, bank-conflict-free).
__device__ __forceinline__ void scan_rows(const float* __restrict__ t, int lo, int hi,
                                          int gofs, const v2f wv2[5],
                                          float& best, int& bidx) {
    int r = lo;
    if ((r & 1) && r < hi) {               // odd leading row: b64 @0, b128 @+8B, b128 @+24B
        v2f c0 = *(const v2f*)(t + r * 10);
        v4f c1 = *(const v4f*)(t + r * 10 + 2);
        v4f c2 = *(const v4f*)(t + r * 10 + 6);
        v2f a = wv2[0] * c0;
        a += wv2[1] * c1.lo; a += wv2[2] * c1.hi;
        a += wv2[3] * c2.lo; a += wv2[4] * c2.hi;
        float s = a.x + a.y;
        if (s > best) { best = s; bidx = gofs + r; }
        ++r;
    }
    #pragma unroll 2
    for (; r + 1 < hi; r += 2) {           // even pair: 80B = exactly 5x b128
        const v4f* p = (const v4f*)(t + r * 10);
        v4f v0 = p[0], v1 = p[1], v2 = p[2], v3 = p[3], v4 = p[4];
        v2f a0 = wv2[0] * v0.lo;
        a0 += wv2[1] * v0.hi; a0 += wv2[2] * v1.lo;
        a0 += wv2[3] * v1.hi; a0 += wv2[4] * v2.lo;
        float s0 = a0.x + a0.y;
        v2f a1 = wv2[0] * v2.hi;
        a1 += wv2[1] * v3.lo; a1 += wv2[2] * v3.hi;
        a1 += wv2[3] * v4.lo; a1 += wv2[4] * v4.hi;
        float s1 = a1.x + a1.y;
        float sp = s0; int np2 = r;
        if (s1 > s0) { sp = s1; np2 = r + 1; }   // strict > keeps earlier index on tie
        if (sp > best) { best = sp; bidx = gofs + np2; }
    }
    if (r < hi) {                          // even trailing row
        v4f c0 = *(const v4f*)(t + r * 10);
        v4f c1 = *(const v4f*)(t + r * 10 + 4);
        v2f c2 = *(const v2f*)(t + r * 10 + 8);
        v2f a = wv2[0] * c0.lo;
        a += wv2[1] * c0.hi; a += wv2[2] * c1.lo;
        a += wv2[3] * c1.hi; a += wv2[4] * c2;
        float s = a.x + a.y;
        if (s > best) { best = s; bidx = gofs + r; }
    }
}

__global__ __launch_bounds__(256, 2) void actor_kernel(
    const int* __restrict__ wid, const int* __restrict__ pid,
    const float* __restrict__ wemb, const float* __restrict__ pemb,
    const float* __restrict__ W1, const float* __restrict__ b1,
    const float* __restrict__ W2, const float* __restrict__ b2,
    int* __restrict__ out)
{
    __shared__ v4f tbl4[F4_A];             // 49840 B -> 2 blocks/CU fit in 160 KB
    __shared__ float sb[4][64];
    __shared__ int   si[4][64];

    const int tid  = threadIdx.x;
    const int lane = tid & 63;
    const int wave = tid >> 6;
    const int g    = wave >> 1;            // element group (0/1): 64 elems each
    const int h    = wave & 1;             // row-half worker within the group
    const int b    = blockIdx.x * 128 + g * 64 + lane;

    // ---- stage chunk A (table rows [0,1246)) as coalesced float4 ----
    const v4f* __restrict__ gA = (const v4f*)pemb;
    #pragma unroll
    for (int k = 0; k < 13; ++k) {
        int idx = tid + (k << 8);
        if (idx < F4_A) tbl4[idx] = gA[idx];
    }

    // ---- per-element MLP (computed redundantly by both h-waves of a group) ----
    const int wi = wid[b];
    const int pi = pid[b];
    const float* __restrict__ wr = wemb + wi * EMB;
    const float* __restrict__ pr = pemb + pi * EMB;
    float x[STATE];
    #pragma unroll
    for (int k = 0; k < EMB / 2; ++k) {
        v2f v = *(const v2f*)(wr + 2 * k);
        x[2 * k] = v.x; x[2 * k + 1] = v.y;
    }
    #pragma unroll
    for (int k = 0; k < EMB / 2; ++k) {
        v2f v = *(const v2f*)(pr + 2 * k);
        x[EMB + 2 * k] = v.x; x[EMB + 2 * k + 1] = v.y;
    }
    float hbuf[HIDDEN];
    #pragma unroll 4
    for (int j = 0; j < HIDDEN; ++j) {     // W1/b1 addresses are block-uniform -> scalar loads
        float s = b1[j];
        #pragma unroll
        for (int k = 0; k < STATE; ++k) s = fmaf(W1[j * STATE + k], x[k], s);
        hbuf[j] = fmaxf(s, 0.0f);
    }
    float wv[EMB];
    #pragma unroll
    for (int d = 0; d < EMB; ++d) {
        float s = b2[d];
        #pragma unroll
        for (int j = 0; j < HIDDEN; ++j) s = fmaf(W2[d * HIDDEN + j], hbuf[j], s);
        wv[d] = s;
    }
    v2f wv2[5];
    #pragma unroll
    for (int k = 0; k < 5; ++k) wv2[k] = (v2f){wv[2 * k], wv[2 * k + 1]};

    float best = -FLT_MAX;
    int   bidx = 1;

    // ---- scan chunk A: h0 -> rows [1,624), h1 -> rows [624,1246) ----
    __syncthreads();
    const float* t = (const float*)tbl4;
    if (h == 0) scan_rows(t, 1, 624, 0, wv2, best, bidx);
    else        scan_rows(t, 624, ROWS_A, 0, wv2, best, bidx);

    // ---- stage chunk B (rows [1246,2490)) ----
    __syncthreads();
    const v4f* __restrict__ gB = gA + F4_A;
    #pragma unroll
    for (int k = 0; k < 13; ++k) {
        int idx = tid + (k << 8);
        if (idx < F4_B) tbl4[idx] = gB[idx];
    }
    __syncthreads();

    // ---- scan chunk B: h0 -> local [0,622), h1 -> local [622,1244) ----
    if (h == 0) scan_rows(t, 0, 622, ROWS_A, wv2, best, bidx);
    else        scan_rows(t, 622, ROWS_B, ROWS_A, wv2, best, bidx);

    // ---- combine the two row-halves (global first-max tie-break via index) ----
    sb[wave][lane] = best;
    si[wave][lane] = bidx;
    __syncthreads();
    if (h == 0) {
        float v  = sb[wave + 1][lane];
        int   vi = si[wave + 1][lane];
        if (v > best || (v == best && vi < bidx)) { best = v; bidx = vi; }
        out[b] = bidx;
    }
}

extern "C" void kernel_launch(void* const* d_in, const int* in_sizes, int n_in,
                              void* d_out, int out_size, void* d_ws, size_t ws_size,
                              hipStream_t stream) {
    const int*   wid  = (const int*)  d_in[0];
    const int*   pid  = (const int*)  d_in[1];
    const float* wemb = (const float*)d_in[2];
    const float* pemb = (const float*)d_in[3];
    const float* W1   = (const float*)d_in[4];
    const float* b1   = (const float*)d_in[5];
    const float* W2   = (const float*)d_in[6];
    const float* b2   = (const float*)d_in[7];
    int* out = (int*)d_out;

    const int B = in_sizes[0];               // 65536
    actor_kernel<<<B / 128, 256, 0, stream>>>(wid, pid, wemb, pemb, W1, b1, W2, b2, out);
}

// Round 3
// 137.081 us; speedup vs baseline: 2.3299x; 1.2044x over previous
//
#include <hip/hip_runtime.h>
#include <float.h>

using v2f = __attribute__((ext_vector_type(2))) float;
using v4f = __attribute__((ext_vector_type(4))) float;

#define EMB 10
#define STATE 20
#define HIDDEN 40
#define NPROJ 2490

// Score one even-aligned row pair (rows 2p, 2p+1). tbl4 is indexed ONLY by the
// uniform loop variable p -> uniform address -> compiler emits s_load_dwordx4;
// row data lives in SGPRs and feeds v_pk_fma_f32 as the one scalar operand.
__device__ __forceinline__ void score_pair(const v4f* __restrict__ tbl4, int p,
                                           const v2f wv2[5],
                                           float& best, int& bidx) {
    const v4f* tp = tbl4 + p * 5;          // pair base: byte 80*p, 16B-aligned
    v4f a0 = tp[0], a1 = tp[1], a2 = tp[2], a3 = tp[3], a4 = tp[4];
    v2f c0 = wv2[0] * a0.lo;
    c0 += wv2[1] * a0.hi; c0 += wv2[2] * a1.lo;
    c0 += wv2[3] * a1.hi; c0 += wv2[4] * a2.lo;
    float s0 = c0.x + c0.y;
    v2f c1 = wv2[0] * a2.hi;
    c1 += wv2[1] * a3.lo; c1 += wv2[2] * a3.hi;
    c1 += wv2[3] * a4.lo; c1 += wv2[4] * a4.hi;
    float s1 = c1.x + c1.y;
    float sp = s0; int ip = 2 * p;
    if (s1 > sp) { sp = s1; ip = 2 * p + 1; }   // strict > : earlier index wins ties
    if (sp > best) { best = sp; bidx = ip; }
}

__global__ __launch_bounds__(256, 2) void actor_kernel(
    const int* __restrict__ wid, const int* __restrict__ pid,
    const float* __restrict__ wemb, const float* __restrict__ pemb,
    const float* __restrict__ W1, const float* __restrict__ b1,
    const float* __restrict__ W2, const float* __restrict__ b2,
    int* __restrict__ out)
{
    __shared__ float sb[4][64];
    __shared__ int   si[4][64];

    const int tid  = threadIdx.x;
    const int lane = tid & 63;
    const int wave = tid >> 6;
    const int g    = wave >> 1;            // element group (2 groups of 64 per block)
    const int h    = wave & 1;             // row-half worker
    const int b    = blockIdx.x * 128 + g * 64 + lane;

    const v4f* __restrict__ tbl4 =
        (const v4f*)__builtin_assume_aligned(pemb, 16);

    // ---- gather x (per-lane, divergent vector loads) ----
    const int wi = wid[b];
    const int pi = pid[b];
    const float* __restrict__ wr = wemb + wi * EMB;
    const float* __restrict__ pr = pemb + pi * EMB;
    v2f x2[STATE / 2];
    #pragma unroll
    for (int k = 0; k < EMB / 2; ++k) x2[k] = *(const v2f*)(wr + 2 * k);
    #pragma unroll
    for (int k = 0; k < EMB / 2; ++k) x2[EMB / 2 + k] = *(const v2f*)(pr + 2 * k);

    // ---- layer 1 (weights uniform -> scalar loads; packed FMA) ----
    float hb[HIDDEN];
    #pragma unroll 4
    for (int j = 0; j < HIDDEN; ++j) {
        const v2f* w1r = (const v2f*)(W1 + j * STATE);
        v2f a = w1r[0] * x2[0];
        #pragma unroll
        for (int k = 1; k < STATE / 2; ++k) a += w1r[k] * x2[k];
        hb[j] = fmaxf(a.x + a.y + b1[j], 0.0f);
    }
    v2f h2[HIDDEN / 2];
    #pragma unroll
    for (int k = 0; k < HIDDEN / 2; ++k) h2[k] = (v2f){hb[2 * k], hb[2 * k + 1]};

    // ---- layer 2 ----
    v2f wv2[5];
    #pragma unroll
    for (int d = 0; d < EMB; d += 2) {
        const v2f* w2r0 = (const v2f*)(W2 + d * HIDDEN);
        const v2f* w2r1 = (const v2f*)(W2 + (d + 1) * HIDDEN);
        v2f a0 = w2r0[0] * h2[0];
        v2f a1 = w2r1[0] * h2[0];
        #pragma unroll
        for (int k = 1; k < HIDDEN / 2; ++k) { a0 += w2r0[k] * h2[k]; a1 += w2r1[k] * h2[k]; }
        wv2[d / 2] = (v2f){a0.x + a0.y + b2[d], a1.x + a1.y + b2[d + 1]};
    }

    float best = -FLT_MAX;
    int   bidx = 1;

    // ---- scan: h0 -> rows [1,1246), h1 -> rows [1246,2490); all via SMEM ----
    if (h == 0) {
        // row 1 alone (row 0 excluded from the table): 8B-aligned loads
        {
            v2f c0v = *(const v2f*)(pemb + 10);
            v4f c1v = *(const v4f*)(pemb + 12);
            v4f c2v = *(const v4f*)(pemb + 16);
            v2f a = wv2[0] * c0v;
            a += wv2[1] * c1v.lo; a += wv2[2] * c1v.hi;
            a += wv2[3] * c2v.lo; a += wv2[4] * c2v.hi;
            best = a.x + a.y; bidx = 1;
        }
        #pragma unroll 4
        for (int p = 1; p < 623; ++p) score_pair(tbl4, p, wv2, best, bidx);
    } else {
        #pragma unroll 4
        for (int p = 623; p < 1245; ++p) score_pair(tbl4, p, wv2, best, bidx);
    }

    // ---- combine halves (h1 indices all higher -> strict > keeps first-max) ----
    sb[wave][lane] = best;
    si[wave][lane] = bidx;
    __syncthreads();
    if (h == 0) {
        float v  = sb[wave + 1][lane];
        int   vi = si[wave + 1][lane];
        if (v > best) { best = v; bidx = vi; }
        out[b] = bidx;
    }
}

extern "C" void kernel_launch(void* const* d_in, const int* in_sizes, int n_in,
                              void* d_out, int out_size, void* d_ws, size_t ws_size,
                              hipStream_t stream) {
    const int*   wid  = (const int*)  d_in[0];
    const int*   pid  = (const int*)  d_in[1];
    const float* wemb = (const float*)d_in[2];
    const float* pemb = (const float*)d_in[3];
    const float* W1   = (const float*)d_in[4];
    const float* b1   = (const float*)d_in[5];
    const float* W2   = (const float*)d_in[6];
    const float* b2   = (const float*)d_in[7];
    int* out = (int*)d_out;

    const int B = in_sizes[0];               // 65536
    actor_kernel<<<B / 128, 256, 0, stream>>>(wid, pid, wemb, pemb, W1, b1, W2, b2, out);
}